// Round 1
// baseline (333.532 us; speedup 1.0000x reference)
//
#include <hip/hip_runtime.h>

#define DIM 1024
#define SEQ 2048
#define HID 128
#define HEADS 8
#define DECAYC 4

typedef __bf16 bf16x8 __attribute__((ext_vector_type(8)));
typedef float f32x4 __attribute__((ext_vector_type(4)));

__device__ __forceinline__ unsigned short f2bf(float f) {
  union { float f; unsigned u; } v; v.f = f;
  unsigned r = v.u + 0x7fffu + ((v.u >> 16) & 1u);
  return (unsigned short)(r >> 16);
}
__device__ __forceinline__ float bf2f(unsigned short u) {
  union { unsigned u; float f; } v; v.u = ((unsigned)u) << 16;
  return v.f;
}

typedef __attribute__((address_space(1))) const unsigned int* g_u32p;
typedef __attribute__((address_space(3))) unsigned int* l_u32p;

__device__ __forceinline__ void async_ld16(const unsigned short* g, unsigned short* l) {
  __builtin_amdgcn_global_load_lds((g_u32p)g, (l_u32p)l, 16, 0, 0);
}

// ---------------- fp32 -> bf16 convert ----------------
__global__ void convertk(const float* __restrict__ in, unsigned short* __restrict__ out, int n) {
  int i = blockIdx.x * 256 + threadIdx.x;
  if (i < n) out[i] = f2bf(in[i]);
}

// ------------- x (B,E,T) f32 -> xT (B,T,E) bf16 -------------
__global__ __launch_bounds__(256) void transpose_x(const float* __restrict__ x,
                                                   unsigned short* __restrict__ xT) {
  __shared__ float tile[64][65];
  const int b = blockIdx.z;
  const int e0 = blockIdx.x * 64;  // 16 tiles over E=1024
  const int t0 = blockIdx.y * 64;  // 32 tiles over T=2048
  const int tr = threadIdx.x >> 6;   // 0..3
  const int tc = threadIdx.x & 63;   // 0..63
  const float* xp = x + ((size_t)b * DIM + e0) * SEQ + t0;
#pragma unroll
  for (int i = 0; i < 16; ++i) {
    int e = i * 4 + tr;
    tile[e][tc] = xp[(size_t)e * SEQ + tc];
  }
  __syncthreads();
  unsigned short* op = xT + ((size_t)b * SEQ + t0) * DIM + e0;
#pragma unroll
  for (int i = 0; i < 16; ++i) {
    int t = i * 4 + tr;
    op[(size_t)t * DIM + tc] = f2bf(tile[tc][t]);
  }
}

// ------------- NT GEMM: C[m][n] = sum_k A[m][k]*B[n][k] + bias -------------
// A: (M,K) bf16 row-major k-contig; B: (N,K) bf16 row-major k-contig.
// 128x128 tile, BK=32, 4 waves (2x2), each wave 4x4 fragments of 16x16x32 MFMA.
template <int C_BF16, int BIAS_ROW>
__global__ __launch_bounds__(256) void gemm_nt(const unsigned short* __restrict__ A,
                                               const unsigned short* __restrict__ B,
                                               void* __restrict__ Cv,
                                               const float* __restrict__ bias,
                                               int lda, int ldb, int ldc, int K,
                                               long sA, long sB, long sC) {
  __shared__ unsigned short lA[128 * 32];
  __shared__ unsigned short lB[128 * 32];

  A += (size_t)sA * blockIdx.z;
  B += (size_t)sB * blockIdx.z;

  const int m0 = blockIdx.x * 128;
  const int n0 = blockIdx.y * 128;
  const int tid = threadIdx.x;
  const int lane = tid & 63;
  const int w = tid >> 6;          // wave 0..3
  const int wr = (w >> 1) * 64;    // wave row offset
  const int wc = (w & 1) * 64;     // wave col offset

  // staging: each wave stages 2 chunks (1KB each) of A and of B
  const int ch0 = w * 2;
  const int srow = ch0 * 16 + (lane >> 2);
  const int skoff = (lane & 3) * 8;

  const unsigned short* gA = A + (size_t)(m0 + srow) * lda + skoff;
  const unsigned short* gA2 = gA + (size_t)16 * lda;
  const unsigned short* gB = B + (size_t)(n0 + srow) * ldb + skoff;
  const unsigned short* gB2 = gB + (size_t)16 * ldb;
  unsigned short* dA = &lA[ch0 * 512];
  unsigned short* dB = &lB[ch0 * 512];

  const int r = lane & 15;
  const int ko = (lane >> 4) * 8;

  f32x4 acc[4][4] = {};

  for (int kt = 0; kt < K; kt += 32) {
    async_ld16(gA + kt, dA);
    async_ld16(gA2 + kt, dA + 512);
    async_ld16(gB + kt, dB);
    async_ld16(gB2 + kt, dB + 512);
    __syncthreads();  // vmcnt(0) drained by compiler before barrier
    bf16x8 af[4], bfr[4];
#pragma unroll
    for (int i = 0; i < 4; ++i) {
      af[i] = *(const bf16x8*)&lA[(wr + i * 16 + r) * 32 + ko];
      bfr[i] = *(const bf16x8*)&lB[(wc + i * 16 + r) * 32 + ko];
    }
#pragma unroll
    for (int i = 0; i < 4; ++i)
#pragma unroll
      for (int j = 0; j < 4; ++j)
        acc[i][j] = __builtin_amdgcn_mfma_f32_16x16x32_bf16(af[i], bfr[j], acc[i][j], 0, 0, 0);
    __syncthreads();  // compute done before next-tile staging overwrites
  }

  // epilogue: D lane mapping col=lane&15, row=(lane>>4)*4+reg  [HW-verified]
  const int or0 = (lane >> 4) * 4;
  const int oc = lane & 15;
#pragma unroll
  for (int i = 0; i < 4; ++i) {
#pragma unroll
    for (int j = 0; j < 4; ++j) {
      const int col = n0 + wc + j * 16 + oc;
      float cbias = BIAS_ROW ? 0.0f : bias[col];
#pragma unroll
      for (int q = 0; q < 4; ++q) {
        const int row = m0 + wr + i * 16 + or0 + q;
        float v = acc[i][j][q] + (BIAS_ROW ? bias[row] : cbias);
        if constexpr (C_BF16) {
          unsigned short* C = (unsigned short*)Cv + (size_t)sC * blockIdx.z;
          C[(size_t)row * ldc + col] = f2bf(v);
        } else {
          float* C = (float*)Cv + (size_t)sC * blockIdx.z;
          C[(size_t)row * ldc + col] = v;
        }
      }
    }
  }
}

// ------------- mixer scan along t -------------
// proj, hidden: (B*SEQ, DIM) bf16, n = h*128+d
__global__ __launch_bounds__(256) void scan_mix(const unsigned short* __restrict__ proj,
                                                unsigned short* __restrict__ hidden,
                                                const float* __restrict__ mix_w,
                                                const float* __restrict__ mix_b,
                                                const float* __restrict__ decay_v) {
  const int idx = blockIdx.x * 256 + threadIdx.x;  // 0..8191
  const int b = idx >> 10;
  const int n = idx & 1023;
  const int h = n >> 7;
  float d = fminf(fmaxf(decay_v[h], 0.9f), 1.0f);
  const float rr = powf(d, 1.0f / (float)DECAYC);
  const bool colrep = (h < (HEADS / 2));
  const unsigned short* p = proj + (size_t)b * SEQ * DIM + n;
  unsigned short* o = hidden + (size_t)b * SEQ * DIM + n;
  const float* mw = mix_w + h * SEQ;
  const float* mb = mix_b + h * SEQ;
  float state = 0.0f;
#pragma unroll 4
  for (int t = 0; t < SEQ; ++t) {
    float v = bf2f(p[(size_t)t * DIM]);
    float wv = mw[t];
    float res;
    if (colrep) {
      state = state * rr + v;
      res = wv * state;
    } else {
      state = state * rr + v * wv;
      res = state;
    }
    o[(size_t)t * DIM] = f2bf(res + mb[t]);
  }
}

extern "C" void kernel_launch(void* const* d_in, const int* in_sizes, int n_in,
                              void* d_out, int out_size, void* d_ws, size_t ws_size,
                              hipStream_t stream) {
  const float* x = (const float*)d_in[0];       // (8,1024,2048)
  const float* proj_w = (const float*)d_in[1];  // (8,128,1024)
  const float* proj_b = (const float*)d_in[2];  // (8,128)
  const float* mix_w = (const float*)d_in[3];   // (8,2048)
  const float* mix_b = (const float*)d_in[4];   // (8,2048)
  const float* decay_v = (const float*)d_in[5]; // (8,)
  const float* out_w = (const float*)d_in[6];   // (1024,1024)
  const float* out_b = (const float*)d_in[7];   // (1024,)

  char* ws = (char*)d_ws;
  unsigned short* xT = (unsigned short*)ws;                       // 33.5 MB (B*T, E) bf16
  unsigned short* proj = (unsigned short*)(ws + 33554432);        // 33.5 MB (B*T, N) bf16
  unsigned short* W1 = (unsigned short*)(ws + 67108864);          // 2 MB
  unsigned short* W2 = (unsigned short*)(ws + 69206016);          // 2 MB
  unsigned short* hidden = xT;  // reuse: xT dead after GEMM1

  const int NW = DIM * DIM;  // 1048576 elems each weight
  convertk<<<dim3((NW + 255) / 256), 256, 0, stream>>>(proj_w, W1, NW);
  convertk<<<dim3((NW + 255) / 256), 256, 0, stream>>>(out_w, W2, NW);
  transpose_x<<<dim3(16, 32, 8), 256, 0, stream>>>(x, xT);

  // GEMM1: proj[(b,t)][n] = sum_e xT[(b,t)][e] * W1[n][e] + proj_b[n]
  gemm_nt<1, 0><<<dim3(16384 / 128, DIM / 128, 1), 256, 0, stream>>>(
      xT, W1, proj, proj_b, DIM, DIM, DIM, DIM, 0, 0, 0);

  // mixer scan
  scan_mix<<<dim3(8 * DIM / 256), 256, 0, stream>>>(proj, hidden, mix_w, mix_b, decay_v);

  // GEMM2 (per batch): out[b][i][s] = sum_k W2[i][k]*hidden[b][s][k] + out_b[i]
  gemm_nt<0, 1><<<dim3(DIM / 128, SEQ / 128, 8), 256, 0, stream>>>(
      W2, hidden, d_out, out_b, DIM, DIM, SEQ, DIM, 0, (long)SEQ * DIM, (long)DIM * SEQ);
}

// Round 2
// 169.946 us; speedup vs baseline: 1.9626x; 1.9626x over previous
//
#include <hip/hip_runtime.h>

#define DIM 1024
#define SEQ 2048
#define HID 128
#define HEADS 8
#define DECAYC 4
#define CHUNK 32
#define NCH (SEQ / CHUNK)  // 64

typedef __bf16 bf16x8 __attribute__((ext_vector_type(8)));
typedef float f32x4 __attribute__((ext_vector_type(4)));
typedef unsigned short u16x4 __attribute__((ext_vector_type(4)));

__device__ __forceinline__ unsigned short f2bf(float f) {
  union { float f; unsigned u; } v; v.f = f;
  unsigned r = v.u + 0x7fffu + ((v.u >> 16) & 1u);
  return (unsigned short)(r >> 16);
}
__device__ __forceinline__ float bf2f(unsigned short u) {
  union { unsigned u; float f; } v; v.u = ((unsigned)u) << 16;
  return v.f;
}

typedef __attribute__((address_space(1))) const unsigned int* g_u32p;
typedef __attribute__((address_space(3))) unsigned int* l_u32p;

__device__ __forceinline__ void async_ld16(const unsigned short* g, unsigned short* l) {
  __builtin_amdgcn_global_load_lds((g_u32p)g, (l_u32p)l, 16, 0, 0);
}

// ---------------- fp32 -> bf16 convert ----------------
__global__ void convertk(const float* __restrict__ in, unsigned short* __restrict__ out, int n) {
  int i = blockIdx.x * 256 + threadIdx.x;
  if (i < n) out[i] = f2bf(in[i]);
}

// ------------- x (B,E,T) f32 -> xT (B,T,E) bf16 -------------
__global__ __launch_bounds__(256) void transpose_x(const float* __restrict__ x,
                                                   unsigned short* __restrict__ xT) {
  __shared__ float tile[64][65];
  const int b = blockIdx.z;
  const int e0 = blockIdx.x * 64;
  const int t0 = blockIdx.y * 64;
  const int tr = threadIdx.x >> 6;
  const int tc = threadIdx.x & 63;
  const float* xp = x + ((size_t)b * DIM + e0) * SEQ + t0;
#pragma unroll
  for (int i = 0; i < 16; ++i) {
    int e = i * 4 + tr;
    tile[e][tc] = xp[(size_t)e * SEQ + tc];
  }
  __syncthreads();
  unsigned short* op = xT + ((size_t)b * SEQ + t0) * DIM + e0;
#pragma unroll
  for (int i = 0; i < 16; ++i) {
    int t = i * 4 + tr;
    op[(size_t)t * DIM + tc] = f2bf(tile[tc][t]);
  }
}

// ------------- NT GEMM: C[m][n] = sum_k A[m][k]*B[n][k] + bias -------------
template <int C_BF16, int BIAS_ROW>
__global__ __launch_bounds__(256) void gemm_nt(const unsigned short* __restrict__ A,
                                               const unsigned short* __restrict__ B,
                                               void* __restrict__ Cv,
                                               const float* __restrict__ bias,
                                               int lda, int ldb, int ldc, int K,
                                               long sA, long sB, long sC) {
  __shared__ unsigned short lA[128 * 32];
  __shared__ unsigned short lB[128 * 32];

  A += (size_t)sA * blockIdx.z;
  B += (size_t)sB * blockIdx.z;

  const int m0 = blockIdx.x * 128;
  const int n0 = blockIdx.y * 128;
  const int tid = threadIdx.x;
  const int lane = tid & 63;
  const int w = tid >> 6;
  const int wr = (w >> 1) * 64;
  const int wc = (w & 1) * 64;

  const int ch0 = w * 2;
  const int srow = ch0 * 16 + (lane >> 2);
  const int skoff = (lane & 3) * 8;

  const unsigned short* gA = A + (size_t)(m0 + srow) * lda + skoff;
  const unsigned short* gA2 = gA + (size_t)16 * lda;
  const unsigned short* gB = B + (size_t)(n0 + srow) * ldb + skoff;
  const unsigned short* gB2 = gB + (size_t)16 * ldb;
  unsigned short* dA = &lA[ch0 * 512];
  unsigned short* dB = &lB[ch0 * 512];

  const int r = lane & 15;
  const int ko = (lane >> 4) * 8;

  f32x4 acc[4][4] = {};

  for (int kt = 0; kt < K; kt += 32) {
    async_ld16(gA + kt, dA);
    async_ld16(gA2 + kt, dA + 512);
    async_ld16(gB + kt, dB);
    async_ld16(gB2 + kt, dB + 512);
    __syncthreads();
    bf16x8 af[4], bfr[4];
#pragma unroll
    for (int i = 0; i < 4; ++i) {
      af[i] = *(const bf16x8*)&lA[(wr + i * 16 + r) * 32 + ko];
      bfr[i] = *(const bf16x8*)&lB[(wc + i * 16 + r) * 32 + ko];
    }
#pragma unroll
    for (int i = 0; i < 4; ++i)
#pragma unroll
      for (int j = 0; j < 4; ++j)
        acc[i][j] = __builtin_amdgcn_mfma_f32_16x16x32_bf16(af[i], bfr[j], acc[i][j], 0, 0, 0);
    __syncthreads();
  }

  const int or0 = (lane >> 4) * 4;
  const int oc = lane & 15;
#pragma unroll
  for (int i = 0; i < 4; ++i) {
#pragma unroll
    for (int j = 0; j < 4; ++j) {
      const int col = n0 + wc + j * 16 + oc;
      float cbias = BIAS_ROW ? 0.0f : bias[col];
#pragma unroll
      for (int q = 0; q < 4; ++q) {
        const int row = m0 + wr + i * 16 + or0 + q;
        float v = acc[i][j][q] + (BIAS_ROW ? bias[row] : cbias);
        if constexpr (C_BF16) {
          unsigned short* C = (unsigned short*)Cv + (size_t)sC * blockIdx.z;
          C[(size_t)row * ldc + col] = f2bf(v);
        } else {
          float* C = (float*)Cv + (size_t)sC * blockIdx.z;
          C[(size_t)row * ldc + col] = v;
        }
      }
    }
  }
}

// ------------- chunked mixer scan -------------
// Phase 1: per-(b,chunk) local scans -> chunk-end carries. Each thread owns 4 n.
__global__ __launch_bounds__(256) void scan_carry(const unsigned short* __restrict__ proj,
                                                  float* __restrict__ carry,
                                                  const float* __restrict__ mix_w,
                                                  const float* __restrict__ decay_v) {
  const int b = blockIdx.x >> 6;
  const int c = blockIdx.x & (NCH - 1);
  const int n0 = threadIdx.x * 4;
  const int h = n0 >> 7;
  const float d = fminf(fmaxf(decay_v[h], 0.9f), 1.0f);
  const float r = powf(d, 1.0f / (float)DECAYC);
  const bool colrep = h < (HEADS / 2);
  const u16x4* p = (const u16x4*)(proj + ((size_t)(b * SEQ + c * CHUNK)) * DIM + n0);
  const float* mw = mix_w + h * SEQ + c * CHUNK;
  float s0 = 0.f, s1 = 0.f, s2 = 0.f, s3 = 0.f;
#pragma unroll 8
  for (int t = 0; t < CHUNK; ++t) {
    u16x4 v = p[t * (DIM / 4)];
    float wi = colrep ? 1.0f : mw[t];
    s0 = s0 * r + bf2f(v[0]) * wi;
    s1 = s1 * r + bf2f(v[1]) * wi;
    s2 = s2 * r + bf2f(v[2]) * wi;
    s3 = s3 * r + bf2f(v[3]) * wi;
  }
  f32x4 out = {s0, s1, s2, s3};
  *(f32x4*)(carry + ((size_t)(b * NCH + c)) * DIM + n0) = out;
}

// Phase 2: exclusive prefix over chunks (in place): carry[c] <- state entering chunk c
__global__ __launch_bounds__(256) void scan_prefix(float* __restrict__ carry,
                                                   const float* __restrict__ decay_v) {
  const int idx = blockIdx.x * 256 + threadIdx.x;  // (b,n), 8192 total
  const int b = idx >> 10;
  const int n = idx & 1023;
  const int h = n >> 7;
  const float d = fminf(fmaxf(decay_v[h], 0.9f), 1.0f);
  const float r = powf(d, 1.0f / (float)DECAYC);
  const float rL = powf(r, (float)CHUNK);
  float P = 0.0f;
  for (int c = 0; c < NCH; ++c) {
    float* p = carry + ((size_t)(b * NCH + c)) * DIM + n;
    float cc = *p;
    *p = P;
    P = rL * P + cc;
  }
}

// Phase 3: replay chunk with carried-in state; write hidden (bf16).
__global__ __launch_bounds__(256) void scan_apply(const unsigned short* __restrict__ proj,
                                                  unsigned short* __restrict__ hidden,
                                                  const float* __restrict__ carry,
                                                  const float* __restrict__ mix_w,
                                                  const float* __restrict__ mix_b,
                                                  const float* __restrict__ decay_v) {
  const int b = blockIdx.x >> 6;
  const int c = blockIdx.x & (NCH - 1);
  const int n0 = threadIdx.x * 4;
  const int h = n0 >> 7;
  const float d = fminf(fmaxf(decay_v[h], 0.9f), 1.0f);
  const float r = powf(d, 1.0f / (float)DECAYC);
  const bool colrep = h < (HEADS / 2);
  const size_t base = ((size_t)(b * SEQ + c * CHUNK)) * DIM + n0;
  const u16x4* p = (const u16x4*)(proj + base);
  u16x4* o = (u16x4*)(hidden + base);
  const float* mw = mix_w + h * SEQ + c * CHUNK;
  const float* mb = mix_b + h * SEQ + c * CHUNK;
  f32x4 ci = *(const f32x4*)(carry + ((size_t)(b * NCH + c)) * DIM + n0);
  float s0 = ci[0], s1 = ci[1], s2 = ci[2], s3 = ci[3];
#pragma unroll 8
  for (int t = 0; t < CHUNK; ++t) {
    u16x4 v = p[t * (DIM / 4)];
    float wv = mw[t];
    float wi = colrep ? 1.0f : wv;
    float wo = colrep ? wv : 1.0f;
    float bb = mb[t];
    s0 = s0 * r + bf2f(v[0]) * wi;
    s1 = s1 * r + bf2f(v[1]) * wi;
    s2 = s2 * r + bf2f(v[2]) * wi;
    s3 = s3 * r + bf2f(v[3]) * wi;
    u16x4 ov;
    ov[0] = f2bf(s0 * wo + bb);
    ov[1] = f2bf(s1 * wo + bb);
    ov[2] = f2bf(s2 * wo + bb);
    ov[3] = f2bf(s3 * wo + bb);
    o[t * (DIM / 4)] = ov;
  }
}

extern "C" void kernel_launch(void* const* d_in, const int* in_sizes, int n_in,
                              void* d_out, int out_size, void* d_ws, size_t ws_size,
                              hipStream_t stream) {
  const float* x = (const float*)d_in[0];
  const float* proj_w = (const float*)d_in[1];
  const float* proj_b = (const float*)d_in[2];
  const float* mix_w = (const float*)d_in[3];
  const float* mix_b = (const float*)d_in[4];
  const float* decay_v = (const float*)d_in[5];
  const float* out_w = (const float*)d_in[6];
  const float* out_b = (const float*)d_in[7];

  char* ws = (char*)d_ws;
  unsigned short* xT = (unsigned short*)ws;                // 33.5 MB (B*T, E) bf16
  unsigned short* proj = (unsigned short*)(ws + 33554432); // 33.5 MB (B*T, N) bf16
  unsigned short* W1 = (unsigned short*)(ws + 67108864);   // 2 MB (dead after GEMM1)
  unsigned short* W2 = (unsigned short*)(ws + 69206016);   // 2 MB
  unsigned short* hidden = xT;                             // reuse: xT dead after GEMM1
  float* carryf = (float*)(ws + 67108864);                 // 2 MB, overlaps W1 (dead)

  const int NW = DIM * DIM;
  convertk<<<dim3((NW + 255) / 256), 256, 0, stream>>>(proj_w, W1, NW);
  convertk<<<dim3((NW + 255) / 256), 256, 0, stream>>>(out_w, W2, NW);
  transpose_x<<<dim3(16, 32, 8), 256, 0, stream>>>(x, xT);

  // GEMM1: proj[(b,t)][n] = sum_e xT[(b,t)][e] * W1[n][e] + proj_b[n]
  gemm_nt<1, 0><<<dim3(16384 / 128, DIM / 128, 1), 256, 0, stream>>>(
      xT, W1, proj, proj_b, DIM, DIM, DIM, DIM, 0, 0, 0);

  // chunked mixer scan
  scan_carry<<<dim3(8 * NCH), 256, 0, stream>>>(proj, carryf, mix_w, decay_v);
  scan_prefix<<<dim3(8192 / 256), 256, 0, stream>>>(carryf, decay_v);
  scan_apply<<<dim3(8 * NCH), 256, 0, stream>>>(proj, hidden, carryf, mix_w, mix_b, decay_v);

  // GEMM2 (per batch): out[b][i][s] = sum_k W2[i][k]*hidden[b][s][k] + out_b[i]
  gemm_nt<0, 1><<<dim3(DIM / 128, SEQ / 128, 8), 256, 0, stream>>>(
      W2, hidden, d_out, out_b, DIM, DIM, SEQ, DIM, 0, (long)SEQ * DIM, (long)DIM * SEQ);
}